// Round 1
// baseline (317.989 us; speedup 1.0000x reference)
//
#include <hip/hip_runtime.h>

#define N_NODES 50000
#define N_EDGES 800000
#define IN_DIM  256
#define OUT_DIM 64

// ---------------- helpers ----------------

__device__ __forceinline__ void atomicMaxFloat(float* addr, float val) {
    // works for mixed signs given init = -inf (0xFF800000)
    if (val >= 0.0f) {
        atomicMax((int*)addr, __float_as_int(val));
    } else {
        atomicMin((unsigned int*)addr, __float_as_uint(val));
    }
}

// ---------------- kernels ----------------

// zero out, init m=-inf, denom=0
__global__ __launch_bounds__(256) void k_init(float* __restrict__ out,
                                              float* __restrict__ m,
                                              float* __restrict__ denom) {
    int idx = blockIdx.x * blockDim.x + threadIdx.x;
    if (idx < N_NODES * OUT_DIM) out[idx] = 0.0f;
    if (idx < N_NODES) {
        m[idx] = __int_as_float(0xFF800000);  // -inf
        denom[idx] = 0.0f;
    }
}

// z = h @ W^T   (h: [N,256], W: [64,256], z: [N,64])
// 64x64 output tile per block, 256 threads, 4x4 per thread, K-chunks of 16.
__global__ __launch_bounds__(256) void k_gemm(const float* __restrict__ h,
                                              const float* __restrict__ W,
                                              float* __restrict__ z) {
    __shared__ __align__(16) float As[64][20];  // [row][k], padded
    __shared__ __align__(16) float Bt[16][68];  // [k][col], padded (transposed W chunk)

    const int t    = threadIdx.x;
    const int row0 = blockIdx.x * 64;
    const int tc   = t & 15;   // col group (4 cols)
    const int tr   = t >> 4;   // row group (4 rows)
    const int lr   = t >> 2;   // staging row/col 0..63
    const int lk   = t & 3;    // staging k-part 0..3

    float acc[4][4] = {};

    for (int kc = 0; kc < IN_DIM; kc += 16) {
        // stage A chunk: As[r][k] = h[row0+r][kc+k]
        float4 av = make_float4(0.f, 0.f, 0.f, 0.f);
        if (row0 + lr < N_NODES)
            av = *(const float4*)&h[(size_t)(row0 + lr) * IN_DIM + kc + lk * 4];
        *(float4*)&As[lr][lk * 4] = av;

        // stage B chunk transposed: Bt[k][j] = W[j][kc+k]
        float4 bv = *(const float4*)&W[(size_t)lr * IN_DIM + kc + lk * 4];
        Bt[lk * 4 + 0][lr] = bv.x;
        Bt[lk * 4 + 1][lr] = bv.y;
        Bt[lk * 4 + 2][lr] = bv.z;
        Bt[lk * 4 + 3][lr] = bv.w;

        __syncthreads();

        #pragma unroll
        for (int kg = 0; kg < 16; kg += 4) {
            float4 a[4], b[4];
            #pragma unroll
            for (int i = 0; i < 4; i++) a[i] = *(const float4*)&As[tr * 4 + i][kg];
            #pragma unroll
            for (int i = 0; i < 4; i++) b[i] = *(const float4*)&Bt[kg + i][tc * 4];
            #pragma unroll
            for (int i = 0; i < 4; i++) {
                const float* ai = (const float*)&a[i];
                #pragma unroll
                for (int kk = 0; kk < 4; kk++) {
                    const float* bk = (const float*)&b[kk];
                    #pragma unroll
                    for (int j = 0; j < 4; j++)
                        acc[i][j] += ai[kk] * bk[j];
                }
            }
        }
        __syncthreads();
    }

    #pragma unroll
    for (int i = 0; i < 4; i++) {
        int row = row0 + tr * 4 + i;
        if (row < N_NODES) {
            float4 o = make_float4(acc[i][0], acc[i][1], acc[i][2], acc[i][3]);
            *(float4*)&z[(size_t)row * OUT_DIM + tc * 4] = o;
        }
    }
}

// a_src[n] = dot(z[n], Wa[0:64]); a_dst[n] = dot(z[n], Wa[64:128])
__global__ __launch_bounds__(256) void k_attn_partials(const float* __restrict__ z,
                                                       const float* __restrict__ Wa,
                                                       float* __restrict__ a_src,
                                                       float* __restrict__ a_dst) {
    int gid  = blockIdx.x * blockDim.x + threadIdx.x;
    int node = gid >> 6;
    int lane = threadIdx.x & 63;
    if (node >= N_NODES) return;
    float v  = z[(size_t)node * OUT_DIM + lane];
    float s1 = v * Wa[lane];
    float s2 = v * Wa[64 + lane];
    #pragma unroll
    for (int off = 32; off; off >>= 1) {
        s1 += __shfl_xor(s1, off);
        s2 += __shfl_xor(s2, off);
    }
    if (lane == 0) {
        a_src[node] = s1;
        a_dst[node] = s2;
    }
}

// per-edge score e = leaky_relu(a_src[s] + a_dst[d]); segment max into m[d]
__global__ __launch_bounds__(256) void k_edge_e(const int* __restrict__ src,
                                                const int* __restrict__ dst,
                                                const float* __restrict__ a_src,
                                                const float* __restrict__ a_dst,
                                                float* __restrict__ e,
                                                float* __restrict__ m) {
    int i = blockIdx.x * blockDim.x + threadIdx.x;
    if (i >= N_EDGES) return;
    int s = src[i], d = dst[i];
    float ev = a_src[s] + a_dst[d];
    ev = ev > 0.0f ? ev : 0.01f * ev;
    e[i] = ev;
    atomicMaxFloat(&m[d], ev);
}

// one wave per edge: w = exp(e - m[d]); denom[d] += w; out[d][:] += w * z[s][:]
__global__ __launch_bounds__(256) void k_edge_accum(const int* __restrict__ src,
                                                    const int* __restrict__ dst,
                                                    const float* __restrict__ e,
                                                    const float* __restrict__ m,
                                                    const float* __restrict__ z,
                                                    float* __restrict__ denom,
                                                    float* __restrict__ out) {
    int gid  = blockIdx.x * blockDim.x + threadIdx.x;
    int i    = gid >> 6;
    int lane = threadIdx.x & 63;
    if (i >= N_EDGES) return;
    int s = src[i], d = dst[i];
    float w = expf(e[i] - m[d]);
    if (lane == 0) atomicAdd(&denom[d], w);
    float val = w * z[(size_t)s * OUT_DIM + lane];
    atomicAdd(&out[(size_t)d * OUT_DIM + lane], val);
}

// normalize: out[n][:] /= max(denom[n], 1e-16)
__global__ __launch_bounds__(256) void k_norm(float* __restrict__ out,
                                              const float* __restrict__ denom) {
    int idx = blockIdx.x * blockDim.x + threadIdx.x;
    if (idx >= N_NODES * OUT_DIM) return;
    out[idx] /= fmaxf(denom[idx >> 6], 1e-16f);
}

// ---------------- launch ----------------

extern "C" void kernel_launch(void* const* d_in, const int* in_sizes, int n_in,
                              void* d_out, int out_size, void* d_ws, size_t ws_size,
                              hipStream_t stream) {
    const float* h      = (const float*)d_in[0];
    const float* W_fc   = (const float*)d_in[1];
    const float* W_attn = (const float*)d_in[2];
    const int*   src    = (const int*)d_in[3];
    const int*   dst    = (const int*)d_in[4];
    float* out = (float*)d_out;

    // workspace layout (floats)
    float* ws    = (float*)d_ws;
    float* z     = ws;                           // N*64
    float* a_src = z + (size_t)N_NODES * OUT_DIM; // N
    float* a_dst = a_src + N_NODES;               // N
    float* e     = a_dst + N_NODES;               // E
    float* m     = e + N_EDGES;                   // N
    float* denom = m + N_NODES;                   // N

    const int nOut = N_NODES * OUT_DIM;

    k_init<<<(nOut + 255) / 256, 256, 0, stream>>>(out, m, denom);
    k_gemm<<<(N_NODES + 63) / 64, 256, 0, stream>>>(h, W_fc, z);
    k_attn_partials<<<((N_NODES * 64) + 255) / 256, 256, 0, stream>>>(z, W_attn, a_src, a_dst);
    k_edge_e<<<(N_EDGES + 255) / 256, 256, 0, stream>>>(src, dst, a_src, a_dst, e, m);
    k_edge_accum<<<((size_t)N_EDGES * 64 + 255) / 256, 256, 0, stream>>>(src, dst, e, m, z, denom, out);
    k_norm<<<(nOut + 255) / 256, 256, 0, stream>>>(out, denom);
}

// Round 2
// 196.511 us; speedup vs baseline: 1.6182x; 1.6182x over previous
//
#include <hip/hip_runtime.h>

#define N_NODES 50000
#define N_EDGES 800000
#define IN_DIM  256
#define OUT_DIM 64

// ---------------- kernels ----------------

// zero the dst-degree histogram
__global__ __launch_bounds__(256) void k_init(int* __restrict__ count) {
    int idx = blockIdx.x * blockDim.x + threadIdx.x;
    if (idx < N_NODES) count[idx] = 0;
}

// z = h @ W^T   (h: [N,256], W: [64,256], z: [N,64])
// 64x64 output tile per block, 256 threads, 4x4 per thread, K-chunks of 16.
__global__ __launch_bounds__(256) void k_gemm(const float* __restrict__ h,
                                              const float* __restrict__ W,
                                              float* __restrict__ z) {
    __shared__ __align__(16) float As[64][20];  // [row][k], padded
    __shared__ __align__(16) float Bt[16][68];  // [k][col], padded (transposed W chunk)

    const int t    = threadIdx.x;
    const int row0 = blockIdx.x * 64;
    const int tc   = t & 15;   // col group (4 cols)
    const int tr   = t >> 4;   // row group (4 rows)
    const int lr   = t >> 2;   // staging row/col 0..63
    const int lk   = t & 3;    // staging k-part 0..3

    float acc[4][4] = {};

    for (int kc = 0; kc < IN_DIM; kc += 16) {
        float4 av = make_float4(0.f, 0.f, 0.f, 0.f);
        if (row0 + lr < N_NODES)
            av = *(const float4*)&h[(size_t)(row0 + lr) * IN_DIM + kc + lk * 4];
        *(float4*)&As[lr][lk * 4] = av;

        float4 bv = *(const float4*)&W[(size_t)lr * IN_DIM + kc + lk * 4];
        Bt[lk * 4 + 0][lr] = bv.x;
        Bt[lk * 4 + 1][lr] = bv.y;
        Bt[lk * 4 + 2][lr] = bv.z;
        Bt[lk * 4 + 3][lr] = bv.w;

        __syncthreads();

        #pragma unroll
        for (int kg = 0; kg < 16; kg += 4) {
            float4 a[4], b[4];
            #pragma unroll
            for (int i = 0; i < 4; i++) a[i] = *(const float4*)&As[tr * 4 + i][kg];
            #pragma unroll
            for (int i = 0; i < 4; i++) b[i] = *(const float4*)&Bt[kg + i][tc * 4];
            #pragma unroll
            for (int i = 0; i < 4; i++) {
                const float* ai = (const float*)&a[i];
                #pragma unroll
                for (int kk = 0; kk < 4; kk++) {
                    const float* bk = (const float*)&b[kk];
                    #pragma unroll
                    for (int j = 0; j < 4; j++)
                        acc[i][j] += ai[kk] * bk[j];
                }
            }
        }
        __syncthreads();
    }

    #pragma unroll
    for (int i = 0; i < 4; i++) {
        int row = row0 + tr * 4 + i;
        if (row < N_NODES) {
            float4 o = make_float4(acc[i][0], acc[i][1], acc[i][2], acc[i][3]);
            *(float4*)&z[(size_t)row * OUT_DIM + tc * 4] = o;
        }
    }
}

// a_src[n] = dot(z[n], Wa[0:64]); a_dst[n] = dot(z[n], Wa[64:128])
__global__ __launch_bounds__(256) void k_attn_partials(const float* __restrict__ z,
                                                       const float* __restrict__ Wa,
                                                       float* __restrict__ a_src,
                                                       float* __restrict__ a_dst) {
    int gid  = blockIdx.x * blockDim.x + threadIdx.x;
    int node = gid >> 6;
    int lane = threadIdx.x & 63;
    if (node >= N_NODES) return;
    float v  = z[(size_t)node * OUT_DIM + lane];
    float s1 = v * Wa[lane];
    float s2 = v * Wa[64 + lane];
    #pragma unroll
    for (int off = 32; off; off >>= 1) {
        s1 += __shfl_xor(s1, off);
        s2 += __shfl_xor(s2, off);
    }
    if (lane == 0) {
        a_src[node] = s1;
        a_dst[node] = s2;
    }
}

// histogram of dst
__global__ __launch_bounds__(256) void k_hist(const int* __restrict__ dst,
                                              int* __restrict__ count) {
    int i = blockIdx.x * blockDim.x + threadIdx.x;
    if (i < N_EDGES) atomicAdd(&count[dst[i]], 1);
}

// block-level exclusive scan of count -> rowptr (per-block), block totals -> bsum
__global__ __launch_bounds__(1024) void k_scan_block(const int* __restrict__ count,
                                                     int* __restrict__ rowptr,
                                                     int* __restrict__ bsum) {
    __shared__ int wsum[16];
    __shared__ int wexcl[16];
    const int tid  = threadIdx.x;
    const int idx  = blockIdx.x * 1024 + tid;
    const int lane = tid & 63;
    const int wid  = tid >> 6;

    int v = (idx < N_NODES) ? count[idx] : 0;
    int incl = v;
    #pragma unroll
    for (int off = 1; off < 64; off <<= 1) {
        int t = __shfl_up(incl, off);
        if (lane >= off) incl += t;
    }
    if (lane == 63) wsum[wid] = incl;
    __syncthreads();
    if (wid == 0) {
        int s  = (lane < 16) ? wsum[lane] : 0;
        int si = s;
        #pragma unroll
        for (int off = 1; off < 16; off <<= 1) {
            int t = __shfl_up(si, off);
            if (lane >= off) si += t;
        }
        if (lane < 16) wexcl[lane] = si - s;
        if (lane == 15) bsum[blockIdx.x] = si;  // block total
    }
    __syncthreads();
    if (idx < N_NODES) rowptr[idx] = incl - v + wexcl[wid];
}

// exclusive scan of <=64 block totals (single wave)
__global__ __launch_bounds__(64) void k_scan_tops(const int* __restrict__ bsum,
                                                  int* __restrict__ boffs, int nb) {
    int lane = threadIdx.x;
    int v = (lane < nb) ? bsum[lane] : 0;
    int incl = v;
    #pragma unroll
    for (int off = 1; off < 64; off <<= 1) {
        int t = __shfl_up(incl, off);
        if (lane >= off) incl += t;
    }
    if (lane < nb) boffs[lane] = incl - v;
}

// add block offsets; zero the cursor (reuses count array); set rowptr[N]=E
__global__ __launch_bounds__(256) void k_scan_add(int* __restrict__ rowptr,
                                                  const int* __restrict__ boffs,
                                                  int* __restrict__ cursor) {
    int idx = blockIdx.x * blockDim.x + threadIdx.x;
    if (idx < N_NODES) {
        rowptr[idx] += boffs[idx >> 10];
        cursor[idx] = 0;
    }
    if (idx == 0) rowptr[N_NODES] = N_EDGES;
}

// scatter edges into CSR slots (only src index needed; e recomputed later)
__global__ __launch_bounds__(256) void k_scatter(const int* __restrict__ src,
                                                 const int* __restrict__ dst,
                                                 const int* __restrict__ rowptr,
                                                 int* __restrict__ cursor,
                                                 int* __restrict__ csr_src) {
    int i = blockIdx.x * blockDim.x + threadIdx.x;
    if (i >= N_EDGES) return;
    int d = dst[i];
    int pos = atomicAdd(&cursor[d], 1);
    csr_src[rowptr[d] + pos] = src[i];
}

// one wave per node: segment softmax + weighted aggregation, no atomics
__global__ __launch_bounds__(256) void k_aggregate(const int* __restrict__ rowptr,
                                                   const int* __restrict__ csr_src,
                                                   const float* __restrict__ a_src,
                                                   const float* __restrict__ a_dst,
                                                   const float* __restrict__ z,
                                                   float* __restrict__ out) {
    int gid  = blockIdx.x * blockDim.x + threadIdx.x;
    int node = gid >> 6;
    int lane = threadIdx.x & 63;
    if (node >= N_NODES) return;

    const int beg = rowptr[node];
    const int end = rowptr[node + 1];
    const float adst = a_dst[node];

    // pass 1: segment max of e = leaky_relu(a_src[s] + adst)
    float mx = -INFINITY;
    for (int j = beg + lane; j < end; j += 64) {
        int s = csr_src[j];
        float ev = a_src[s] + adst;
        ev = ev > 0.0f ? ev : 0.01f * ev;
        mx = fmaxf(mx, ev);
    }
    #pragma unroll
    for (int off = 32; off; off >>= 1) mx = fmaxf(mx, __shfl_xor(mx, off));

    // pass 2: chunked exp + broadcast-accumulate
    float dn = 0.0f, acc = 0.0f;
    for (int base = beg; base < end; base += 64) {
        int rem = end - base; if (rem > 64) rem = 64;
        float w = 0.0f; int sj = 0;
        if (lane < rem) {
            sj = csr_src[base + lane];
            float ev = a_src[sj] + adst;
            ev = ev > 0.0f ? ev : 0.01f * ev;
            w = __expf(ev - mx);
        }
        dn += w;
        for (int k = 0; k < rem; ++k) {
            float wk = __shfl(w, k);
            int   sk = __shfl(sj, k);
            acc += wk * z[(size_t)sk * OUT_DIM + lane];
        }
    }
    #pragma unroll
    for (int off = 32; off; off >>= 1) dn += __shfl_xor(dn, off);

    out[(size_t)node * OUT_DIM + lane] = acc / fmaxf(dn, 1e-16f);
}

// ---------------- launch ----------------

extern "C" void kernel_launch(void* const* d_in, const int* in_sizes, int n_in,
                              void* d_out, int out_size, void* d_ws, size_t ws_size,
                              hipStream_t stream) {
    const float* h      = (const float*)d_in[0];
    const float* W_fc   = (const float*)d_in[1];
    const float* W_attn = (const float*)d_in[2];
    const int*   src    = (const int*)d_in[3];
    const int*   dst    = (const int*)d_in[4];
    float* out = (float*)d_out;

    // workspace layout
    float* ws      = (float*)d_ws;
    float* z       = ws;                            // N*64 floats
    float* a_src   = z + (size_t)N_NODES * OUT_DIM; // N
    float* a_dst   = a_src + N_NODES;               // N
    int*   rowptr  = (int*)(a_dst + N_NODES);       // N+1
    int*   count   = rowptr + (N_NODES + 1);        // N (doubles as cursor)
    int*   bsum    = count + N_NODES;               // 64
    int*   boffs   = bsum + 64;                     // 64
    int*   csr_src = boffs + 64;                    // E

    const int NB_SCAN = (N_NODES + 1023) / 1024;    // 49

    k_init<<<(N_NODES + 255) / 256, 256, 0, stream>>>(count);
    k_gemm<<<(N_NODES + 63) / 64, 256, 0, stream>>>(h, W_fc, z);
    k_attn_partials<<<((N_NODES * 64) + 255) / 256, 256, 0, stream>>>(z, W_attn, a_src, a_dst);
    k_hist<<<(N_EDGES + 255) / 256, 256, 0, stream>>>(dst, count);
    k_scan_block<<<NB_SCAN, 1024, 0, stream>>>(count, rowptr, bsum);
    k_scan_tops<<<1, 64, 0, stream>>>(bsum, boffs, NB_SCAN);
    k_scan_add<<<(N_NODES + 255) / 256, 256, 0, stream>>>(rowptr, boffs, count);
    k_scatter<<<(N_EDGES + 255) / 256, 256, 0, stream>>>(src, dst, rowptr, count, csr_src);
    k_aggregate<<<((size_t)N_NODES * 64 + 255) / 256, 256, 0, stream>>>(rowptr, csr_src, a_src, a_dst, z, out);
}

// Round 3
// 132.163 us; speedup vs baseline: 2.4060x; 1.4869x over previous
//
#include <hip/hip_runtime.h>

#define N_NODES 50000
#define N_EDGES 800000
#define IN_DIM  256
#define OUT_DIM 64
#define NB_SCAN ((N_NODES + 1023) / 1024)   // 49

// ---------------- kernels ----------------

// z = h @ W^T  fused with attn partials.
// 64x64 tile per block, 256 threads, 4x4 per thread, K-chunks of 32.
// Epilogue: a_src[n] = dot(z[n], Wa[0:64]); a_dst[n] = dot(z[n], Wa[64:128])
__global__ __launch_bounds__(256) void k_gemm_attn(const float* __restrict__ h,
                                                   const float* __restrict__ W,
                                                   const float* __restrict__ Wa,
                                                   float* __restrict__ z,
                                                   float* __restrict__ a_src,
                                                   float* __restrict__ a_dst) {
    __shared__ __align__(16) float As[64][36];  // [row][k], padded
    __shared__ __align__(16) float Bt[32][68];  // [k][col], padded

    const int t    = threadIdx.x;
    const int row0 = blockIdx.x * 64;
    const int tc   = t & 15;   // col group (4 cols)
    const int tr   = t >> 4;   // row group (4 rows)

    float acc[4][4] = {};

    for (int kc = 0; kc < IN_DIM; kc += 32) {
        // stage A: 512 float4s, 2 per thread: As[row][kp*4..] = h[row0+row][kc+kp*4..]
        #pragma unroll
        for (int q = 0; q < 2; ++q) {
            int f   = t + q * 256;
            int row = f >> 3, kp = f & 7;
            float4 av = make_float4(0.f, 0.f, 0.f, 0.f);
            if (row0 + row < N_NODES)
                av = *(const float4*)&h[(size_t)(row0 + row) * IN_DIM + kc + kp * 4];
            *(float4*)&As[row][kp * 4] = av;
        }
        // stage B transposed: Bt[k][j] = W[j][kc+k]
        #pragma unroll
        for (int q = 0; q < 2; ++q) {
            int f = t + q * 256;
            int j = f >> 3, kp = f & 7;
            float4 bv = *(const float4*)&W[(size_t)j * IN_DIM + kc + kp * 4];
            Bt[kp * 4 + 0][j] = bv.x;
            Bt[kp * 4 + 1][j] = bv.y;
            Bt[kp * 4 + 2][j] = bv.z;
            Bt[kp * 4 + 3][j] = bv.w;
        }
        __syncthreads();

        #pragma unroll
        for (int kg = 0; kg < 32; kg += 4) {
            float4 a[4], b[4];
            #pragma unroll
            for (int i = 0; i < 4; i++) a[i] = *(const float4*)&As[tr * 4 + i][kg];
            #pragma unroll
            for (int i = 0; i < 4; i++) b[i] = *(const float4*)&Bt[kg + i][tc * 4];
            #pragma unroll
            for (int i = 0; i < 4; i++) {
                const float* ai = (const float*)&a[i];
                #pragma unroll
                for (int kk = 0; kk < 4; kk++) {
                    const float* bk = (const float*)&b[kk];
                    #pragma unroll
                    for (int j = 0; j < 4; j++)
                        acc[i][j] += ai[kk] * bk[j];
                }
            }
        }
        __syncthreads();
    }

    // store z tile
    #pragma unroll
    for (int i = 0; i < 4; i++) {
        int row = row0 + tr * 4 + i;
        if (row < N_NODES) {
            float4 o = make_float4(acc[i][0], acc[i][1], acc[i][2], acc[i][3]);
            *(float4*)&z[(size_t)row * OUT_DIM + tc * 4] = o;
        }
    }

    // fused attn partials: reduce acc rows against Wa across the 16 tc lanes
    float4 was = *(const float4*)&Wa[tc * 4];
    float4 wad = *(const float4*)&Wa[64 + tc * 4];
    #pragma unroll
    for (int i = 0; i < 4; i++) {
        float s1 = acc[i][0] * was.x + acc[i][1] * was.y + acc[i][2] * was.z + acc[i][3] * was.w;
        float s2 = acc[i][0] * wad.x + acc[i][1] * wad.y + acc[i][2] * wad.z + acc[i][3] * wad.w;
        #pragma unroll
        for (int off = 8; off; off >>= 1) {
            s1 += __shfl_xor(s1, off);
            s2 += __shfl_xor(s2, off);
        }
        int row = row0 + tr * 4 + i;
        if (tc == 0 && row < N_NODES) {
            a_src[row] = s1;
            a_dst[row] = s2;
        }
    }
}

// histogram of dst; also records each edge's within-segment position
__global__ __launch_bounds__(256) void k_hist(const int* __restrict__ dst,
                                              int* __restrict__ count,
                                              int* __restrict__ pos) {
    int i = blockIdx.x * blockDim.x + threadIdx.x;
    if (i < N_EDGES) pos[i] = atomicAdd(&count[dst[i]], 1);
}

// block-level exclusive scan of count -> rowptr (per-block), block totals -> bsum
__global__ __launch_bounds__(1024) void k_scan_block(const int* __restrict__ count,
                                                     int* __restrict__ rowptr,
                                                     int* __restrict__ bsum) {
    __shared__ int wsum[16];
    __shared__ int wexcl[16];
    const int tid  = threadIdx.x;
    const int idx  = blockIdx.x * 1024 + tid;
    const int lane = tid & 63;
    const int wid  = tid >> 6;

    int v = (idx < N_NODES) ? count[idx] : 0;
    int incl = v;
    #pragma unroll
    for (int off = 1; off < 64; off <<= 1) {
        int u = __shfl_up(incl, off);
        if (lane >= off) incl += u;
    }
    if (lane == 63) wsum[wid] = incl;
    __syncthreads();
    if (wid == 0) {
        int s  = (lane < 16) ? wsum[lane] : 0;
        int si = s;
        #pragma unroll
        for (int off = 1; off < 16; off <<= 1) {
            int u = __shfl_up(si, off);
            if (lane >= off) si += u;
        }
        if (lane < 16) wexcl[lane] = si - s;
        if (lane == 15) bsum[blockIdx.x] = si;  // block total
    }
    __syncthreads();
    if (idx < N_NODES) rowptr[idx] = incl - v + wexcl[wid];
}

// add block offsets (top-level 49-entry scan recomputed in wave 0); rowptr[N]=E
__global__ __launch_bounds__(256) void k_scan_add(int* __restrict__ rowptr,
                                                  const int* __restrict__ bsum) {
    __shared__ int sboffs[64];
    const int tid = threadIdx.x;
    if (tid < 64) {
        int v = (tid < NB_SCAN) ? bsum[tid] : 0;
        int incl = v;
        #pragma unroll
        for (int off = 1; off < 64; off <<= 1) {
            int u = __shfl_up(incl, off);
            if (tid >= off) incl += u;
        }
        sboffs[tid] = incl - v;
    }
    __syncthreads();
    int idx = blockIdx.x * 256 + tid;
    if (idx < N_NODES) rowptr[idx] += sboffs[idx >> 10];
    if (idx == 0) rowptr[N_NODES] = N_EDGES;
}

// scatter edges into CSR slots — no atomics (uses recorded pos)
__global__ __launch_bounds__(256) void k_scatter(const int* __restrict__ src,
                                                 const int* __restrict__ dst,
                                                 const int* __restrict__ rowptr,
                                                 const int* __restrict__ pos,
                                                 int* __restrict__ csr_src) {
    int i = blockIdx.x * blockDim.x + threadIdx.x;
    if (i >= N_EDGES) return;
    csr_src[rowptr[dst[i]] + pos[i]] = src[i];
}

// one wave per node: segment softmax + weighted aggregation, no atomics.
// Fast path deg<=64: (w, src) staged in LDS, inner loop = ds_read_b64 broadcast
// + coalesced z row load + FMA, unrolled x8 with zero-padded tail.
__global__ __launch_bounds__(256) void k_aggregate(const int* __restrict__ rowptr,
                                                   const int* __restrict__ csr_src,
                                                   const float* __restrict__ a_src,
                                                   const float* __restrict__ a_dst,
                                                   const float* __restrict__ z,
                                                   float* __restrict__ out) {
    __shared__ float2 buf[4][64];
    const int wid  = threadIdx.x >> 6;
    const int lane = threadIdx.x & 63;
    const int node = blockIdx.x * 4 + wid;
    if (node >= N_NODES) return;

    const int beg = rowptr[node];
    const int end = rowptr[node + 1];
    const int deg = end - beg;
    const float adst = a_dst[node];

    float acc = 0.0f, dn = 0.0f;

    if (deg <= 64) {
        int s = 0;
        float ev = -INFINITY;
        if (lane < deg) {
            s = csr_src[beg + lane];
            float u = a_src[s] + adst;
            ev = u > 0.0f ? u : 0.01f * u;
        }
        float mx = ev;
        #pragma unroll
        for (int off = 32; off; off >>= 1) mx = fmaxf(mx, __shfl_xor(mx, off));

        float w = (lane < deg) ? __expf(ev - mx) : 0.0f;
        dn = w;
        #pragma unroll
        for (int off = 32; off; off >>= 1) dn += __shfl_xor(dn, off);

        buf[wid][lane] = make_float2(w, __int_as_float(s));
        __builtin_amdgcn_wave_barrier();

        const int kmax = (deg + 7) & ~7;  // padded entries have w=0
        for (int k = 0; k < kmax; k += 8) {
            #pragma unroll
            for (int u = 0; u < 8; ++u) {
                float2 p = buf[wid][k + u];
                acc = fmaf(p.x, z[(size_t)__float_as_int(p.y) * OUT_DIM + lane], acc);
            }
        }
    } else {
        // general path (not expected for this graph, kept for correctness)
        float mx = -INFINITY;
        for (int j = beg + lane; j < end; j += 64) {
            int s = csr_src[j];
            float u = a_src[s] + adst;
            u = u > 0.0f ? u : 0.01f * u;
            mx = fmaxf(mx, u);
        }
        #pragma unroll
        for (int off = 32; off; off >>= 1) mx = fmaxf(mx, __shfl_xor(mx, off));

        for (int base = beg; base < end; base += 64) {
            int rem = end - base; if (rem > 64) rem = 64;
            int s = 0; float w = 0.0f;
            if (lane < rem) {
                s = csr_src[base + lane];
                float u = a_src[s] + adst;
                u = u > 0.0f ? u : 0.01f * u;
                w = __expf(u - mx);
            }
            dn += w;
            __builtin_amdgcn_wave_barrier();
            buf[wid][lane] = make_float2(w, __int_as_float(s));
            __builtin_amdgcn_wave_barrier();
            int kmax = (rem + 7) & ~7;
            for (int k = 0; k < kmax; k += 8) {
                #pragma unroll
                for (int u = 0; u < 8; ++u) {
                    float2 p = buf[wid][k + u];
                    acc = fmaf(p.x, z[(size_t)__float_as_int(p.y) * OUT_DIM + lane], acc);
                }
            }
            __builtin_amdgcn_wave_barrier();
        }
        #pragma unroll
        for (int off = 32; off; off >>= 1) dn += __shfl_xor(dn, off);
    }

    out[(size_t)node * OUT_DIM + lane] = acc / fmaxf(dn, 1e-16f);
}

// ---------------- launch ----------------

extern "C" void kernel_launch(void* const* d_in, const int* in_sizes, int n_in,
                              void* d_out, int out_size, void* d_ws, size_t ws_size,
                              hipStream_t stream) {
    const float* h      = (const float*)d_in[0];
    const float* W_fc   = (const float*)d_in[1];
    const float* W_attn = (const float*)d_in[2];
    const int*   src    = (const int*)d_in[3];
    const int*   dst    = (const int*)d_in[4];
    float* out = (float*)d_out;

    // workspace layout
    float* ws      = (float*)d_ws;
    float* z       = ws;                            // N*64 floats
    float* a_src   = z + (size_t)N_NODES * OUT_DIM; // N
    float* a_dst   = a_src + N_NODES;               // N
    int*   rowptr  = (int*)(a_dst + N_NODES);       // N+1
    int*   count   = rowptr + (N_NODES + 1);        // N
    int*   bsum    = count + N_NODES;               // 64
    int*   pos     = bsum + 64;                     // E
    int*   csr_src = pos + N_EDGES;                 // E

    hipMemsetAsync(count, 0, N_NODES * sizeof(int), stream);
    k_gemm_attn<<<(N_NODES + 63) / 64, 256, 0, stream>>>(h, W_fc, W_attn, z, a_src, a_dst);
    k_hist<<<(N_EDGES + 255) / 256, 256, 0, stream>>>(dst, count, pos);
    k_scan_block<<<NB_SCAN, 1024, 0, stream>>>(count, rowptr, bsum);
    k_scan_add<<<(N_NODES + 255) / 256, 256, 0, stream>>>(rowptr, bsum);
    k_scatter<<<(N_EDGES + 255) / 256, 256, 0, stream>>>(src, dst, rowptr, pos, csr_src);
    k_aggregate<<<(N_NODES + 3) / 4, 256, 0, stream>>>(rowptr, csr_src, a_src, a_dst, z, out);
}

// Round 4
// 109.501 us; speedup vs baseline: 2.9040x; 1.2070x over previous
//
#include <hip/hip_runtime.h>

#define N_NODES 50000
#define N_EDGES 800000
#define IN_DIM  256
#define OUT_DIM 64
#define NB_SCAN ((N_NODES + 1023) / 1024)   // 49

typedef _Float16 f16;
typedef __attribute__((ext_vector_type(4))) _Float16 f16x4;
typedef __attribute__((ext_vector_type(8))) _Float16 f16x8;
typedef __attribute__((ext_vector_type(4))) float f32x4;

// ---------------- kernels ----------------

// z(f16) = h @ W^T via f16 MFMA, fused with attn partials + count zeroing.
// 64-row tile per block, 4 waves; W (64x256) entirely in LDS as f16;
// A staged in K-chunks of 128. XOR-swizzle (elem ^= (row&7)<<3) on both sides.
__global__ __launch_bounds__(256) void k_gemm_attn(const float* __restrict__ h,
                                                   const float* __restrict__ W,
                                                   const float* __restrict__ Wa,
                                                   f16* __restrict__ z,
                                                   float* __restrict__ a_src,
                                                   float* __restrict__ a_dst,
                                                   int* __restrict__ count) {
    __shared__ __align__(16) f16 Wl[64 * 256];   // [col][k], swizzled
    __shared__ __align__(16) f16 Al[64 * 128];   // [row][k-chunk], swizzled

    const int t    = threadIdx.x;
    const int row0 = blockIdx.x * 64;
    const int lane = t & 63;
    const int wid  = t >> 6;

    // fused: zero dst-degree counters (blocks 0..195 cover all 50000)
    if (blockIdx.x < 196) {
        int idx = blockIdx.x * 256 + t;
        if (idx < N_NODES) count[idx] = 0;
    }

    // stage W: fp32 -> f16, swizzled. 4096 float4s, 16 per thread.
    #pragma unroll
    for (int i = 0; i < 16; ++i) {
        int f    = i * 256 + t;
        int col  = f >> 6, slot = f & 63;
        float4 v = *(const float4*)&W[(size_t)f * 4];
        f16x4 p  = { (f16)v.x, (f16)v.y, (f16)v.z, (f16)v.w };
        *(f16x4*)&Wl[(col * 256 + slot * 4) ^ ((col & 7) << 3)] = p;
    }

    f32x4 acc[4] = {};

    for (int kc = 0; kc < IN_DIM; kc += 128) {
        // stage A chunk: 64 rows x 128 k, fp32 -> f16, swizzled
        #pragma unroll
        for (int i = 0; i < 8; ++i) {
            int f   = i * 256 + t;
            int row = f >> 5, slot = f & 31;
            float4 v = make_float4(0.f, 0.f, 0.f, 0.f);
            if (row0 + row < N_NODES)
                v = *(const float4*)&h[(size_t)(row0 + row) * IN_DIM + kc + slot * 4];
            f16x4 p = { (f16)v.x, (f16)v.y, (f16)v.z, (f16)v.w };
            *(f16x4*)&Al[(row * 128 + slot * 4) ^ ((row & 7) << 3)] = p;
        }
        __syncthreads();

        #pragma unroll
        for (int ks = 0; ks < 4; ++ks) {
            const int arow = wid * 16 + (lane & 15);
            const int ak   = ks * 32 + (lane >> 4) * 8;
            f16x8 a = *(const f16x8*)&Al[(arow * 128 + ak) ^ ((arow & 7) << 3)];
            #pragma unroll
            for (int ct = 0; ct < 4; ++ct) {
                const int col = ct * 16 + (lane & 15);
                const int bk  = kc + ks * 32 + (lane >> 4) * 8;
                f16x8 b = *(const f16x8*)&Wl[(col * 256 + bk) ^ ((col & 7) << 3)];
                acc[ct] = __builtin_amdgcn_mfma_f32_16x16x32_f16(a, b, acc[ct], 0, 0, 0);
            }
        }
        __syncthreads();
    }

    // epilogue: store z (f16) — C/D layout: col=lane&15, row=(lane>>4)*4+r
    const int cl    = lane & 15;
    const int rbase = row0 + wid * 16 + (lane >> 4) * 4;
    #pragma unroll
    for (int ct = 0; ct < 4; ++ct) {
        #pragma unroll
        for (int r = 0; r < 4; ++r) {
            int row = rbase + r;
            if (row < N_NODES)
                z[(size_t)row * OUT_DIM + ct * 16 + cl] = (f16)acc[ct][r];
        }
    }

    // fused attn partials: a_src/a_dst row dots, reduce over the 16 col lanes
    float wa1[4], wa2[4];
    #pragma unroll
    for (int ct = 0; ct < 4; ++ct) {
        wa1[ct] = Wa[ct * 16 + cl];
        wa2[ct] = Wa[64 + ct * 16 + cl];
    }
    #pragma unroll
    for (int r = 0; r < 4; ++r) {
        float s1 = 0.f, s2 = 0.f;
        #pragma unroll
        for (int ct = 0; ct < 4; ++ct) {
            s1 += acc[ct][r] * wa1[ct];
            s2 += acc[ct][r] * wa2[ct];
        }
        #pragma unroll
        for (int off = 1; off < 16; off <<= 1) {
            s1 += __shfl_xor(s1, off);
            s2 += __shfl_xor(s2, off);
        }
        int row = rbase + r;
        if (cl == 0 && row < N_NODES) {
            a_src[row] = s1;
            a_dst[row] = s2;
        }
    }
}

// histogram of dst; also records each edge's within-segment position
__global__ __launch_bounds__(256) void k_hist(const int* __restrict__ dst,
                                              int* __restrict__ count,
                                              int* __restrict__ pos) {
    int i = blockIdx.x * blockDim.x + threadIdx.x;
    if (i < N_EDGES) pos[i] = atomicAdd(&count[dst[i]], 1);
}

// block-level exclusive scan of count -> rowptr (per-block), block totals -> bsum
__global__ __launch_bounds__(1024) void k_scan_block(const int* __restrict__ count,
                                                     int* __restrict__ rowptr,
                                                     int* __restrict__ bsum) {
    __shared__ int wsum[16];
    __shared__ int wexcl[16];
    const int tid  = threadIdx.x;
    const int idx  = blockIdx.x * 1024 + tid;
    const int lane = tid & 63;
    const int wid  = tid >> 6;

    int v = (idx < N_NODES) ? count[idx] : 0;
    int incl = v;
    #pragma unroll
    for (int off = 1; off < 64; off <<= 1) {
        int u = __shfl_up(incl, off);
        if (lane >= off) incl += u;
    }
    if (lane == 63) wsum[wid] = incl;
    __syncthreads();
    if (wid == 0) {
        int s  = (lane < 16) ? wsum[lane] : 0;
        int si = s;
        #pragma unroll
        for (int off = 1; off < 16; off <<= 1) {
            int u = __shfl_up(si, off);
            if (lane >= off) si += u;
        }
        if (lane < 16) wexcl[lane] = si - s;
        if (lane == 15) bsum[blockIdx.x] = si;  // block total
    }
    __syncthreads();
    if (idx < N_NODES) rowptr[idx] = incl - v + wexcl[wid];
}

// add block offsets (top-level 49-entry scan recomputed in wave 0); rowptr[N]=E
__global__ __launch_bounds__(256) void k_scan_add(int* __restrict__ rowptr,
                                                  const int* __restrict__ bsum) {
    __shared__ int sboffs[64];
    const int tid = threadIdx.x;
    if (tid < 64) {
        int v = (tid < NB_SCAN) ? bsum[tid] : 0;
        int incl = v;
        #pragma unroll
        for (int off = 1; off < 64; off <<= 1) {
            int u = __shfl_up(incl, off);
            if (tid >= off) incl += u;
        }
        sboffs[tid] = incl - v;
    }
    __syncthreads();
    int idx = blockIdx.x * 256 + tid;
    if (idx < N_NODES) rowptr[idx] += sboffs[idx >> 10];
    if (idx == 0) rowptr[N_NODES] = N_EDGES;
}

// scatter edges into CSR slots — no atomics (uses recorded pos)
__global__ __launch_bounds__(256) void k_scatter(const int* __restrict__ src,
                                                 const int* __restrict__ dst,
                                                 const int* __restrict__ rowptr,
                                                 const int* __restrict__ pos,
                                                 int* __restrict__ csr_src) {
    int i = blockIdx.x * blockDim.x + threadIdx.x;
    if (i >= N_EDGES) return;
    csr_src[rowptr[dst[i]] + pos[i]] = src[i];
}

// one wave per node: segment softmax + weighted aggregation, no atomics.
// Inner loop: 4 edges per wave, 16 lanes x f16x4 per edge-row, (w,src) in LDS.
__global__ __launch_bounds__(256) void k_aggregate(const int* __restrict__ rowptr,
                                                   const int* __restrict__ csr_src,
                                                   const float* __restrict__ a_src,
                                                   const float* __restrict__ a_dst,
                                                   const f16* __restrict__ z,
                                                   float* __restrict__ out) {
    __shared__ float2 buf[4][64];
    const int wid  = threadIdx.x >> 6;
    const int lane = threadIdx.x & 63;
    const int node = blockIdx.x * 4 + wid;
    if (node >= N_NODES) return;

    const int beg = rowptr[node];
    const int end = rowptr[node + 1];
    const float adst = a_dst[node];

    // pass 1: segment max of e = leaky_relu(a_src[s] + adst)
    float mx = -INFINITY;
    for (int j = beg + lane; j < end; j += 64) {
        int s = csr_src[j];
        float u = a_src[s] + adst;
        u = u > 0.0f ? u : 0.01f * u;
        mx = fmaxf(mx, u);
    }
    #pragma unroll
    for (int off = 32; off; off >>= 1) mx = fmaxf(mx, __shfl_xor(mx, off));

    // pass 2: per-64 chunk: stage (w,src), then 4-edges-per-wave f16x4 gather
    const int grp = lane >> 4;       // 0..3: which edge in the quad
    const int cl  = lane & 15;       // 0..15: which float4-of-f16 column group
    float dn = 0.0f;
    float4 acc4 = make_float4(0.f, 0.f, 0.f, 0.f);

    for (int base = beg; base < end; base += 64) {
        int rem = end - base; if (rem > 64) rem = 64;
        int s = 0; float w = 0.0f;
        if (lane < rem) {
            s = csr_src[base + lane];
            float u = a_src[s] + adst;
            u = u > 0.0f ? u : 0.01f * u;
            w = __expf(u - mx);
        }
        dn += w;
        __builtin_amdgcn_wave_barrier();
        buf[wid][lane] = make_float2(w, __int_as_float(s));
        __builtin_amdgcn_wave_barrier();

        const int kmax = (rem + 3) & ~3;   // padded entries have w=0, s=0
        for (int k = 0; k < kmax; k += 4) {
            float2 p = buf[wid][k + grp];
            int   sk = __float_as_int(p.y);
            float wk = p.x;
            f16x4 zv = *(const f16x4*)&z[(size_t)sk * OUT_DIM + cl * 4];
            acc4.x = fmaf(wk, (float)zv[0], acc4.x);
            acc4.y = fmaf(wk, (float)zv[1], acc4.y);
            acc4.z = fmaf(wk, (float)zv[2], acc4.z);
            acc4.w = fmaf(wk, (float)zv[3], acc4.w);
        }
        __builtin_amdgcn_wave_barrier();
    }

    // reduce denom across all 64 lanes
    #pragma unroll
    for (int off = 32; off; off >>= 1) dn += __shfl_xor(dn, off);
    // reduce acc4 across the 4 edge-groups
    #pragma unroll
    for (int off = 16; off < 64; off <<= 1) {
        acc4.x += __shfl_xor(acc4.x, off);
        acc4.y += __shfl_xor(acc4.y, off);
        acc4.z += __shfl_xor(acc4.z, off);
        acc4.w += __shfl_xor(acc4.w, off);
    }

    if (lane < 16) {
        float inv = 1.0f / fmaxf(dn, 1e-16f);
        float4 o = make_float4(acc4.x * inv, acc4.y * inv, acc4.z * inv, acc4.w * inv);
        *(float4*)&out[(size_t)node * OUT_DIM + cl * 4] = o;
    }
}

// ---------------- launch ----------------

extern "C" void kernel_launch(void* const* d_in, const int* in_sizes, int n_in,
                              void* d_out, int out_size, void* d_ws, size_t ws_size,
                              hipStream_t stream) {
    const float* h      = (const float*)d_in[0];
    const float* W_fc   = (const float*)d_in[1];
    const float* W_attn = (const float*)d_in[2];
    const int*   src    = (const int*)d_in[3];
    const int*   dst    = (const int*)d_in[4];
    float* out = (float*)d_out;

    // workspace layout
    f16*   z       = (f16*)d_ws;                          // N*64 f16
    float* a_src   = (float*)(z + (size_t)N_NODES * OUT_DIM); // N
    float* a_dst   = a_src + N_NODES;                     // N
    int*   rowptr  = (int*)(a_dst + N_NODES);             // N+1
    int*   count   = rowptr + (N_NODES + 1);              // N
    int*   bsum    = count + N_NODES;                     // 64
    int*   pos     = bsum + 64;                           // E
    int*   csr_src = pos + N_EDGES;                       // E

    k_gemm_attn<<<(N_NODES + 63) / 64, 256, 0, stream>>>(h, W_fc, W_attn, z, a_src, a_dst, count);
    k_hist<<<(N_EDGES + 255) / 256, 256, 0, stream>>>(dst, count, pos);
    k_scan_block<<<NB_SCAN, 1024, 0, stream>>>(count, rowptr, bsum);
    k_scan_add<<<(N_NODES + 255) / 256, 256, 0, stream>>>(rowptr, bsum);
    k_scatter<<<(N_EDGES + 255) / 256, 256, 0, stream>>>(src, dst, rowptr, pos, csr_src);
    k_aggregate<<<(N_NODES + 3) / 4, 256, 0, stream>>>(rowptr, csr_src, a_src, a_dst, z, out);
}

// Round 5
// 108.184 us; speedup vs baseline: 2.9393x; 1.0122x over previous
//
#include <hip/hip_runtime.h>

#define N_NODES 50000
#define N_EDGES 800000
#define IN_DIM  256
#define OUT_DIM 64
#define NB_SCAN ((N_NODES + 1023) / 1024)   // 49

typedef _Float16 f16;
typedef __attribute__((ext_vector_type(4))) _Float16 f16x4;
typedef __attribute__((ext_vector_type(8))) _Float16 f16x8;
typedef __attribute__((ext_vector_type(4))) float f32x4;

// ---------------- kernels ----------------

// zero dst-degree counters (must precede the fused histogram's atomics)
__global__ __launch_bounds__(256) void k_zero(int* __restrict__ count) {
    int idx = blockIdx.x * 256 + threadIdx.x;
    if (idx < N_NODES) count[idx] = 0;
}

// z(f16) = h @ W^T via f16 MFMA, fused with attn partials AND the dst
// histogram (atomic latency hidden under the MFMA K-loop).
// 64-row tile per block, 4 waves; W (64x256) entirely in LDS as f16;
// A staged in K-chunks of 128. XOR-swizzle (elem ^= (row&7)<<3) on both sides.
__global__ __launch_bounds__(256) void k_gemm_attn(const float* __restrict__ h,
                                                   const float* __restrict__ W,
                                                   const float* __restrict__ Wa,
                                                   const int* __restrict__ dst,
                                                   f16* __restrict__ z,
                                                   float* __restrict__ a_src,
                                                   float* __restrict__ a_dst,
                                                   int* __restrict__ count,
                                                   int* __restrict__ pos) {
    __shared__ __align__(16) f16 Wl[64 * 256];   // [col][k], swizzled
    __shared__ __align__(16) f16 Al[64 * 128];   // [row][k-chunk], swizzled

    const int t    = threadIdx.x;
    const int row0 = blockIdx.x * 64;
    const int lane = t & 63;
    const int wid  = t >> 6;

    // --- fused histogram: issue atomics now, consume returns at kernel end ---
    const int gid = blockIdx.x * 256 + t;
    int4 pvec;
    const bool do_hist = (gid < N_EDGES / 4);
    if (do_hist) {
        int4 dvec = ((const int4*)dst)[gid];
        pvec.x = atomicAdd(&count[dvec.x], 1);
        pvec.y = atomicAdd(&count[dvec.y], 1);
        pvec.z = atomicAdd(&count[dvec.z], 1);
        pvec.w = atomicAdd(&count[dvec.w], 1);
    }

    // stage W: fp32 -> f16, swizzled. 4096 float4s, 16 per thread.
    #pragma unroll
    for (int i = 0; i < 16; ++i) {
        int f    = i * 256 + t;
        int col  = f >> 6, slot = f & 63;
        float4 v = *(const float4*)&W[(size_t)f * 4];
        f16x4 p  = { (f16)v.x, (f16)v.y, (f16)v.z, (f16)v.w };
        *(f16x4*)&Wl[(col * 256 + slot * 4) ^ ((col & 7) << 3)] = p;
    }

    f32x4 acc[4] = {};

    for (int kc = 0; kc < IN_DIM; kc += 128) {
        // stage A chunk: 64 rows x 128 k, fp32 -> f16, swizzled
        #pragma unroll
        for (int i = 0; i < 8; ++i) {
            int f   = i * 256 + t;
            int row = f >> 5, slot = f & 31;
            float4 v = make_float4(0.f, 0.f, 0.f, 0.f);
            if (row0 + row < N_NODES)
                v = *(const float4*)&h[(size_t)(row0 + row) * IN_DIM + kc + slot * 4];
            f16x4 p = { (f16)v.x, (f16)v.y, (f16)v.z, (f16)v.w };
            *(f16x4*)&Al[(row * 128 + slot * 4) ^ ((row & 7) << 3)] = p;
        }
        __syncthreads();

        #pragma unroll
        for (int ks = 0; ks < 4; ++ks) {
            const int arow = wid * 16 + (lane & 15);
            const int ak   = ks * 32 + (lane >> 4) * 8;
            f16x8 a = *(const f16x8*)&Al[(arow * 128 + ak) ^ ((arow & 7) << 3)];
            #pragma unroll
            for (int ct = 0; ct < 4; ++ct) {
                const int col = ct * 16 + (lane & 15);
                const int bk  = kc + ks * 32 + (lane >> 4) * 8;
                f16x8 b = *(const f16x8*)&Wl[(col * 256 + bk) ^ ((col & 7) << 3)];
                acc[ct] = __builtin_amdgcn_mfma_f32_16x16x32_f16(a, b, acc[ct], 0, 0, 0);
            }
        }
        __syncthreads();
    }

    // epilogue: store z (f16) — C/D layout: col=lane&15, row=(lane>>4)*4+r
    const int cl    = lane & 15;
    const int rbase = row0 + wid * 16 + (lane >> 4) * 4;
    #pragma unroll
    for (int ct = 0; ct < 4; ++ct) {
        #pragma unroll
        for (int r = 0; r < 4; ++r) {
            int row = rbase + r;
            if (row < N_NODES)
                z[(size_t)row * OUT_DIM + ct * 16 + cl] = (f16)acc[ct][r];
        }
    }

    // fused attn partials: a_src/a_dst row dots, reduce over the 16 col lanes
    float wa1[4], wa2[4];
    #pragma unroll
    for (int ct = 0; ct < 4; ++ct) {
        wa1[ct] = Wa[ct * 16 + cl];
        wa2[ct] = Wa[64 + ct * 16 + cl];
    }
    #pragma unroll
    for (int r = 0; r < 4; ++r) {
        float s1 = 0.f, s2 = 0.f;
        #pragma unroll
        for (int ct = 0; ct < 4; ++ct) {
            s1 += acc[ct][r] * wa1[ct];
            s2 += acc[ct][r] * wa2[ct];
        }
        #pragma unroll
        for (int off = 1; off < 16; off <<= 1) {
            s1 += __shfl_xor(s1, off);
            s2 += __shfl_xor(s2, off);
        }
        int row = rbase + r;
        if (cl == 0 && row < N_NODES) {
            a_src[row] = s1;
            a_dst[row] = s2;
        }
    }

    // --- consume histogram returns (latency long drained by now) ---
    if (do_hist) ((int4*)pos)[gid] = pvec;
}

// block-level exclusive scan of count -> rowptr (per-block), block totals -> bsum
__global__ __launch_bounds__(1024) void k_scan_block(const int* __restrict__ count,
                                                     int* __restrict__ rowptr,
                                                     int* __restrict__ bsum) {
    __shared__ int wsum[16];
    __shared__ int wexcl[16];
    const int tid  = threadIdx.x;
    const int idx  = blockIdx.x * 1024 + tid;
    const int lane = tid & 63;
    const int wid  = tid >> 6;

    int v = (idx < N_NODES) ? count[idx] : 0;
    int incl = v;
    #pragma unroll
    for (int off = 1; off < 64; off <<= 1) {
        int u = __shfl_up(incl, off);
        if (lane >= off) incl += u;
    }
    if (lane == 63) wsum[wid] = incl;
    __syncthreads();
    if (wid == 0) {
        int s  = (lane < 16) ? wsum[lane] : 0;
        int si = s;
        #pragma unroll
        for (int off = 1; off < 16; off <<= 1) {
            int u = __shfl_up(si, off);
            if (lane >= off) si += u;
        }
        if (lane < 16) wexcl[lane] = si - s;
        if (lane == 15) bsum[blockIdx.x] = si;  // block total
    }
    __syncthreads();
    if (idx < N_NODES) rowptr[idx] = incl - v + wexcl[wid];
}

// add block offsets (top-level 49-entry scan recomputed in wave 0); rowptr[N]=E
__global__ __launch_bounds__(256) void k_scan_add(int* __restrict__ rowptr,
                                                  const int* __restrict__ bsum) {
    __shared__ int sboffs[64];
    const int tid = threadIdx.x;
    if (tid < 64) {
        int v = (tid < NB_SCAN) ? bsum[tid] : 0;
        int incl = v;
        #pragma unroll
        for (int off = 1; off < 64; off <<= 1) {
            int u = __shfl_up(incl, off);
            if (tid >= off) incl += u;
        }
        sboffs[tid] = incl - v;
    }
    __syncthreads();
    int idx = blockIdx.x * 256 + tid;
    if (idx < N_NODES) rowptr[idx] += sboffs[idx >> 10];
    if (idx == 0) rowptr[N_NODES] = N_EDGES;
}

// scatter edges into CSR slots — no atomics (uses recorded pos)
__global__ __launch_bounds__(256) void k_scatter(const int* __restrict__ src,
                                                 const int* __restrict__ dst,
                                                 const int* __restrict__ rowptr,
                                                 const int* __restrict__ pos,
                                                 int* __restrict__ csr_src) {
    int i = blockIdx.x * blockDim.x + threadIdx.x;
    if (i >= N_EDGES) return;
    csr_src[rowptr[dst[i]] + pos[i]] = src[i];
}

// one wave per node: segment softmax + weighted aggregation, no atomics.
// Fast path deg<=64 (always true for this graph): single csr_src/a_src read.
// Inner loop: 4 edges per wave, 16 lanes x f16x4 per edge-row, (w,src) in LDS.
__global__ __launch_bounds__(256) void k_aggregate(const int* __restrict__ rowptr,
                                                   const int* __restrict__ csr_src,
                                                   const float* __restrict__ a_src,
                                                   const float* __restrict__ a_dst,
                                                   const f16* __restrict__ z,
                                                   float* __restrict__ out) {
    __shared__ float2 buf[4][64];
    const int wid  = threadIdx.x >> 6;
    const int lane = threadIdx.x & 63;
    const int node = blockIdx.x * 4 + wid;
    if (node >= N_NODES) return;

    const int beg = rowptr[node];
    const int end = rowptr[node + 1];
    const int deg = end - beg;
    const float adst = a_dst[node];

    const int grp = lane >> 4;       // 0..3: which edge in the quad
    const int cl  = lane & 15;       // 0..15: which f16x4 column group
    float dn = 0.0f;
    float4 acc4 = make_float4(0.f, 0.f, 0.f, 0.f);

    if (deg <= 64) {
        int s = 0;
        float ev = -INFINITY;
        if (lane < deg) {
            s = csr_src[beg + lane];
            float u = a_src[s] + adst;
            ev = u > 0.0f ? u : 0.01f * u;
        }
        float mx = ev;
        #pragma unroll
        for (int off = 32; off; off >>= 1) mx = fmaxf(mx, __shfl_xor(mx, off));

        float w = (lane < deg) ? __expf(ev - mx) : 0.0f;
        dn = w;
        #pragma unroll
        for (int off = 32; off; off >>= 1) dn += __shfl_xor(dn, off);

        buf[wid][lane] = make_float2(w, __int_as_float(s));
        __builtin_amdgcn_wave_barrier();

        const int kmax = (deg + 3) & ~3;   // padded entries have w=0, s=0
        for (int k = 0; k < kmax; k += 4) {
            float2 p = buf[wid][k + grp];
            int   sk = __float_as_int(p.y);
            float wk = p.x;
            f16x4 zv = *(const f16x4*)&z[(size_t)sk * OUT_DIM + cl * 4];
            acc4.x = fmaf(wk, (float)zv[0], acc4.x);
            acc4.y = fmaf(wk, (float)zv[1], acc4.y);
            acc4.z = fmaf(wk, (float)zv[2], acc4.z);
            acc4.w = fmaf(wk, (float)zv[3], acc4.w);
        }
    } else {
        // general path (kept for correctness on any graph)
        float mx = -INFINITY;
        for (int j = beg + lane; j < end; j += 64) {
            int s = csr_src[j];
            float u = a_src[s] + adst;
            u = u > 0.0f ? u : 0.01f * u;
            mx = fmaxf(mx, u);
        }
        #pragma unroll
        for (int off = 32; off; off >>= 1) mx = fmaxf(mx, __shfl_xor(mx, off));

        for (int base = beg; base < end; base += 64) {
            int rem = end - base; if (rem > 64) rem = 64;
            int s = 0; float w = 0.0f;
            if (lane < rem) {
                s = csr_src[base + lane];
                float u = a_src[s] + adst;
                u = u > 0.0f ? u : 0.01f * u;
                w = __expf(u - mx);
            }
            dn += w;
            __builtin_amdgcn_wave_barrier();
            buf[wid][lane] = make_float2(w, __int_as_float(s));
            __builtin_amdgcn_wave_barrier();

            const int kmax = (rem + 3) & ~3;
            for (int k = 0; k < kmax; k += 4) {
                float2 p = buf[wid][k + grp];
                int   sk = __float_as_int(p.y);
                float wk = p.x;
                f16x4 zv = *(const f16x4*)&z[(size_t)sk * OUT_DIM + cl * 4];
                acc4.x = fmaf(wk, (float)zv[0], acc4.x);
                acc4.y = fmaf(wk, (float)zv[1], acc4.y);
                acc4.z = fmaf(wk, (float)zv[2], acc4.z);
                acc4.w = fmaf(wk, (float)zv[3], acc4.w);
            }
            __builtin_amdgcn_wave_barrier();
        }
        #pragma unroll
        for (int off = 32; off; off >>= 1) dn += __shfl_xor(dn, off);
    }

    // reduce acc4 across the 4 edge-groups
    #pragma unroll
    for (int off = 16; off < 64; off <<= 1) {
        acc4.x += __shfl_xor(acc4.x, off);
        acc4.y += __shfl_xor(acc4.y, off);
        acc4.z += __shfl_xor(acc4.z, off);
        acc4.w += __shfl_xor(acc4.w, off);
    }

    if (lane < 16) {
        float inv = 1.0f / fmaxf(dn, 1e-16f);
        float4 o = make_float4(acc4.x * inv, acc4.y * inv, acc4.z * inv, acc4.w * inv);
        *(float4*)&out[(size_t)node * OUT_DIM + cl * 4] = o;
    }
}

// ---------------- launch ----------------

extern "C" void kernel_launch(void* const* d_in, const int* in_sizes, int n_in,
                              void* d_out, int out_size, void* d_ws, size_t ws_size,
                              hipStream_t stream) {
    const float* h      = (const float*)d_in[0];
    const float* W_fc   = (const float*)d_in[1];
    const float* W_attn = (const float*)d_in[2];
    const int*   src    = (const int*)d_in[3];
    const int*   dst    = (const int*)d_in[4];
    float* out = (float*)d_out;

    // workspace layout
    f16*   z       = (f16*)d_ws;                              // N*64 f16
    float* a_src   = (float*)(z + (size_t)N_NODES * OUT_DIM); // N
    float* a_dst   = a_src + N_NODES;                         // N
    int*   rowptr  = (int*)(a_dst + N_NODES);                 // N+1
    int*   count   = rowptr + (N_NODES + 1);                  // N
    int*   bsum    = count + N_NODES;                         // 64
    int*   pos     = bsum + 64;                               // E
    int*   csr_src = pos + N_EDGES;                           // E

    k_zero<<<(N_NODES + 255) / 256, 256, 0, stream>>>(count);
    k_gemm_attn<<<(N_NODES + 63) / 64, 256, 0, stream>>>(h, W_fc, W_attn, dst, z, a_src, a_dst, count, pos);
    k_scan_block<<<NB_SCAN, 1024, 0, stream>>>(count, rowptr, bsum);
    k_scan_add<<<(N_NODES + 255) / 256, 256, 0, stream>>>(rowptr, bsum);
    k_scatter<<<(N_EDGES + 255) / 256, 256, 0, stream>>>(src, dst, rowptr, pos, csr_src);
    k_aggregate<<<(N_NODES + 3) / 4, 256, 0, stream>>>(rowptr, csr_src, a_src, a_dst, z, out);
}

// Round 6
// 106.406 us; speedup vs baseline: 2.9885x; 1.0167x over previous
//
#include <hip/hip_runtime.h>

#define N_NODES 50000
#define N_EDGES 800000
#define IN_DIM  256
#define OUT_DIM 64
#define NB_SCAN ((N_NODES + 1023) / 1024)   // 49
#define NB_GEMM ((N_NODES + 63) / 64)       // 782
#define GRID_FUSED 1182                     // 788 gemm-role (>=782) + 394 hist-role

typedef _Float16 f16;
typedef __attribute__((ext_vector_type(4))) _Float16 f16x4;
typedef __attribute__((ext_vector_type(8))) _Float16 f16x8;
typedef __attribute__((ext_vector_type(4))) float f32x4;

// ---------------- kernels ----------------

// zero dst-degree counters + convert W (fp32 -> f16, same row-major layout)
__global__ __launch_bounds__(256) void k_prep(const float* __restrict__ W,
                                              f16* __restrict__ Wh,
                                              int* __restrict__ count) {
    int idx = blockIdx.x * 256 + threadIdx.x;   // grid covers 50176
    if (idx < N_NODES) count[idx] = 0;
    if (idx < (OUT_DIM * IN_DIM) / 4) {
        float4 v = ((const float4*)W)[idx];
        f16x4 p = { (f16)v.x, (f16)v.y, (f16)v.z, (f16)v.w };
        ((f16x4*)Wh)[idx] = p;
    }
}

// Heterogeneous grid: blockIdx%3==2 -> histogram block (pure atomics, no LDS
// use); else GEMM block: z(f16) = h @ W^T via f16 MFMA + fused attn partials.
// GEMM: 64-row tile, 4 waves, A staged in LDS (16KB, XOR-swizzled), B frags
// loaded directly from Wh in global (L2-resident, frag-exact 16B loads).
__global__ __launch_bounds__(256) void k_fused(const float* __restrict__ h,
                                               const f16* __restrict__ Wh,
                                               const float* __restrict__ Wa,
                                               const int* __restrict__ dst,
                                               f16* __restrict__ z,
                                               float* __restrict__ a_src,
                                               float* __restrict__ a_dst,
                                               int* __restrict__ count,
                                               int* __restrict__ pos) {
    const int g = blockIdx.x;
    const int t = threadIdx.x;

    if (g % 3 == 2) {
        // ---- histogram role: 2048 edges per block via int4 ----
        const int hb = g / 3;                 // 0..393
        #pragma unroll
        for (int q = 0; q < 2; ++q) {
            int idx = hb * 512 + q * 256 + t; // int4 index
            if (idx < N_EDGES / 4) {
                int4 dv = ((const int4*)dst)[idx];
                int4 pv;
                pv.x = atomicAdd(&count[dv.x], 1);
                pv.y = atomicAdd(&count[dv.y], 1);
                pv.z = atomicAdd(&count[dv.z], 1);
                pv.w = atomicAdd(&count[dv.w], 1);
                ((int4*)pos)[idx] = pv;
            }
        }
        return;
    }

    // ---- GEMM role ----
    const int gemm_id = (g / 3) * 2 + (g % 3);
    if (gemm_id >= NB_GEMM) return;

    __shared__ __align__(16) f16 Al[64 * 128];   // [row][k-chunk], swizzled

    const int row0 = gemm_id * 64;
    const int lane = t & 63;
    const int wid  = t >> 6;
    const int cl    = lane & 15;
    const int khalf = lane >> 4;

    f32x4 acc[4] = {};

    for (int kc = 0; kc < IN_DIM; kc += 128) {
        // stage A chunk: 64 rows x 128 k, fp32 -> f16, swizzled
        #pragma unroll
        for (int i = 0; i < 8; ++i) {
            int f   = i * 256 + t;
            int row = f >> 5, slot = f & 31;
            float4 v = make_float4(0.f, 0.f, 0.f, 0.f);
            if (row0 + row < N_NODES)
                v = *(const float4*)&h[(size_t)(row0 + row) * IN_DIM + kc + slot * 4];
            f16x4 p = { (f16)v.x, (f16)v.y, (f16)v.z, (f16)v.w };
            *(f16x4*)&Al[(row * 128 + slot * 4) ^ ((row & 7) << 3)] = p;
        }
        __syncthreads();

        #pragma unroll
        for (int ks = 0; ks < 4; ++ks) {
            const int arow = wid * 16 + cl;
            const int ak   = ks * 32 + khalf * 8;
            f16x8 a = *(const f16x8*)&Al[(arow * 128 + ak) ^ ((arow & 7) << 3)];
            #pragma unroll
            for (int ct = 0; ct < 4; ++ct) {
                const int col = ct * 16 + cl;
                const int bk  = kc + ks * 32 + khalf * 8;
                f16x8 b = *(const f16x8*)&Wh[col * 256 + bk];
                acc[ct] = __builtin_amdgcn_mfma_f32_16x16x32_f16(a, b, acc[ct], 0, 0, 0);
            }
        }
        __syncthreads();
    }

    // epilogue: store z (f16) — C/D layout: col=lane&15, row=(lane>>4)*4+r
    const int rbase = row0 + wid * 16 + khalf * 4;
    #pragma unroll
    for (int ct = 0; ct < 4; ++ct) {
        #pragma unroll
        for (int r = 0; r < 4; ++r) {
            int row = rbase + r;
            if (row < N_NODES)
                z[(size_t)row * OUT_DIM + ct * 16 + cl] = (f16)acc[ct][r];
        }
    }

    // fused attn partials: a_src/a_dst row dots, reduce over the 16 col lanes
    float wa1[4], wa2[4];
    #pragma unroll
    for (int ct = 0; ct < 4; ++ct) {
        wa1[ct] = Wa[ct * 16 + cl];
        wa2[ct] = Wa[64 + ct * 16 + cl];
    }
    #pragma unroll
    for (int r = 0; r < 4; ++r) {
        float s1 = 0.f, s2 = 0.f;
        #pragma unroll
        for (int ct = 0; ct < 4; ++ct) {
            s1 += acc[ct][r] * wa1[ct];
            s2 += acc[ct][r] * wa2[ct];
        }
        #pragma unroll
        for (int off = 1; off < 16; off <<= 1) {
            s1 += __shfl_xor(s1, off);
            s2 += __shfl_xor(s2, off);
        }
        int row = rbase + r;
        if (cl == 0 && row < N_NODES) {
            a_src[row] = s1;
            a_dst[row] = s2;
        }
    }
}

// block-level exclusive scan of count -> rowptr (per-block), block totals -> bsum
__global__ __launch_bounds__(1024) void k_scan_block(const int* __restrict__ count,
                                                     int* __restrict__ rowptr,
                                                     int* __restrict__ bsum) {
    __shared__ int wsum[16];
    __shared__ int wexcl[16];
    const int tid  = threadIdx.x;
    const int idx  = blockIdx.x * 1024 + tid;
    const int lane = tid & 63;
    const int wid  = tid >> 6;

    int v = (idx < N_NODES) ? count[idx] : 0;
    int incl = v;
    #pragma unroll
    for (int off = 1; off < 64; off <<= 1) {
        int u = __shfl_up(incl, off);
        if (lane >= off) incl += u;
    }
    if (lane == 63) wsum[wid] = incl;
    __syncthreads();
    if (wid == 0) {
        int s  = (lane < 16) ? wsum[lane] : 0;
        int si = s;
        #pragma unroll
        for (int off = 1; off < 16; off <<= 1) {
            int u = __shfl_up(si, off);
            if (lane >= off) si += u;
        }
        if (lane < 16) wexcl[lane] = si - s;
        if (lane == 15) bsum[blockIdx.x] = si;  // block total
    }
    __syncthreads();
    if (idx < N_NODES) rowptr[idx] = incl - v + wexcl[wid];
}

// add block offsets (top-level 49-entry scan recomputed in wave 0); rowptr[N]=E
__global__ __launch_bounds__(256) void k_scan_add(int* __restrict__ rowptr,
                                                  const int* __restrict__ bsum) {
    __shared__ int sboffs[64];
    const int tid = threadIdx.x;
    if (tid < 64) {
        int v = (tid < NB_SCAN) ? bsum[tid] : 0;
        int incl = v;
        #pragma unroll
        for (int off = 1; off < 64; off <<= 1) {
            int u = __shfl_up(incl, off);
            if (tid >= off) incl += u;
        }
        sboffs[tid] = incl - v;
    }
    __syncthreads();
    int idx = blockIdx.x * 256 + tid;
    if (idx < N_NODES) rowptr[idx] += sboffs[idx >> 10];
    if (idx == 0) rowptr[N_NODES] = N_EDGES;
}

// scatter edges into CSR slots — no atomics (uses recorded pos)
__global__ __launch_bounds__(256) void k_scatter(const int* __restrict__ src,
                                                 const int* __restrict__ dst,
                                                 const int* __restrict__ rowptr,
                                                 const int* __restrict__ pos,
                                                 int* __restrict__ csr_src) {
    int i = blockIdx.x * blockDim.x + threadIdx.x;
    if (i >= N_EDGES) return;
    csr_src[rowptr[dst[i]] + pos[i]] = src[i];
}

// one wave per node: segment softmax + weighted aggregation, no atomics.
// Fast path deg<=64: single csr_src/a_src read; 4 edges per wave,
// 16 lanes x f16x4 per edge-row, (w,src) staged in LDS.
__global__ __launch_bounds__(256) void k_aggregate(const int* __restrict__ rowptr,
                                                   const int* __restrict__ csr_src,
                                                   const float* __restrict__ a_src,
                                                   const float* __restrict__ a_dst,
                                                   const f16* __restrict__ z,
                                                   float* __restrict__ out) {
    __shared__ float2 buf[4][64];
    const int wid  = threadIdx.x >> 6;
    const int lane = threadIdx.x & 63;
    const int node = blockIdx.x * 4 + wid;
    if (node >= N_NODES) return;

    const int beg = rowptr[node];
    const int end = rowptr[node + 1];
    const int deg = end - beg;
    const float adst = a_dst[node];

    const int grp = lane >> 4;       // 0..3: which edge in the quad
    const int cl  = lane & 15;       // 0..15: which f16x4 column group
    float dn = 0.0f;
    float4 acc4 = make_float4(0.f, 0.f, 0.f, 0.f);

    if (deg <= 64) {
        int s = 0;
        float ev = -INFINITY;
        if (lane < deg) {
            s = csr_src[beg + lane];
            float u = a_src[s] + adst;
            ev = u > 0.0f ? u : 0.01f * u;
        }
        float mx = ev;
        #pragma unroll
        for (int off = 32; off; off >>= 1) mx = fmaxf(mx, __shfl_xor(mx, off));

        float w = (lane < deg) ? __expf(ev - mx) : 0.0f;
        dn = w;
        #pragma unroll
        for (int off = 32; off; off >>= 1) dn += __shfl_xor(dn, off);

        buf[wid][lane] = make_float2(w, __int_as_float(s));
        __builtin_amdgcn_wave_barrier();

        const int kmax = (deg + 3) & ~3;   // padded entries have w=0, s=0
        for (int k = 0; k < kmax; k += 4) {
            float2 p = buf[wid][k + grp];
            int   sk = __float_as_int(p.y);
            float wk = p.x;
            f16x4 zv = *(const f16x4*)&z[(size_t)sk * OUT_DIM + cl * 4];
            acc4.x = fmaf(wk, (float)zv[0], acc4.x);
            acc4.y = fmaf(wk, (float)zv[1], acc4.y);
            acc4.z = fmaf(wk, (float)zv[2], acc4.z);
            acc4.w = fmaf(wk, (float)zv[3], acc4.w);
        }
    } else {
        // general path (kept for correctness on any graph)
        float mx = -INFINITY;
        for (int j = beg + lane; j < end; j += 64) {
            int s = csr_src[j];
            float u = a_src[s] + adst;
            u = u > 0.0f ? u : 0.01f * u;
            mx = fmaxf(mx, u);
        }
        #pragma unroll
        for (int off = 32; off; off >>= 1) mx = fmaxf(mx, __shfl_xor(mx, off));

        for (int base = beg; base < end; base += 64) {
            int rem = end - base; if (rem > 64) rem = 64;
            int s = 0; float w = 0.0f;
            if (lane < rem) {
                s = csr_src[base + lane];
                float u = a_src[s] + adst;
                u = u > 0.0f ? u : 0.01f * u;
                w = __expf(u - mx);
            }
            dn += w;
            __builtin_amdgcn_wave_barrier();
            buf[wid][lane] = make_float2(w, __int_as_float(s));
            __builtin_amdgcn_wave_barrier();

            const int kmax = (rem + 3) & ~3;
            for (int k = 0; k < kmax; k += 4) {
                float2 p = buf[wid][k + grp];
                int   sk = __float_as_int(p.y);
                float wk = p.x;
                f16x4 zv = *(const f16x4*)&z[(size_t)sk * OUT_DIM + cl * 4];
                acc4.x = fmaf(wk, (float)zv[0], acc4.x);
                acc4.y = fmaf(wk, (float)zv[1], acc4.y);
                acc4.z = fmaf(wk, (float)zv[2], acc4.z);
                acc4.w = fmaf(wk, (float)zv[3], acc4.w);
            }
            __builtin_amdgcn_wave_barrier();
        }
        #pragma unroll
        for (int off = 32; off; off >>= 1) dn += __shfl_xor(dn, off);
    }

    // reduce acc4 across the 4 edge-groups
    #pragma unroll
    for (int off = 16; off < 64; off <<= 1) {
        acc4.x += __shfl_xor(acc4.x, off);
        acc4.y += __shfl_xor(acc4.y, off);
        acc4.z += __shfl_xor(acc4.z, off);
        acc4.w += __shfl_xor(acc4.w, off);
    }

    if (lane < 16) {
        float inv = 1.0f / fmaxf(dn, 1e-16f);
        float4 o = make_float4(acc4.x * inv, acc4.y * inv, acc4.z * inv, acc4.w * inv);
        *(float4*)&out[(size_t)node * OUT_DIM + cl * 4] = o;
    }
}

// ---------------- launch ----------------

extern "C" void kernel_launch(void* const* d_in, const int* in_sizes, int n_in,
                              void* d_out, int out_size, void* d_ws, size_t ws_size,
                              hipStream_t stream) {
    const float* h      = (const float*)d_in[0];
    const float* W_fc   = (const float*)d_in[1];
    const float* W_attn = (const float*)d_in[2];
    const int*   src    = (const int*)d_in[3];
    const int*   dst    = (const int*)d_in[4];
    float* out = (float*)d_out;

    // workspace layout
    f16*   z       = (f16*)d_ws;                              // N*64 f16
    f16*   Wh      = z + (size_t)N_NODES * OUT_DIM;           // 64*256 f16
    float* a_src   = (float*)(Wh + OUT_DIM * IN_DIM);         // N
    float* a_dst   = a_src + N_NODES;                         // N
    int*   rowptr  = (int*)(a_dst + N_NODES);                 // N+1
    int*   count   = rowptr + (N_NODES + 1);                  // N
    int*   bsum    = count + N_NODES;                         // 64
    int*   pos     = bsum + 64;                               // E
    int*   csr_src = pos + N_EDGES;                           // E

    k_prep<<<(N_NODES + 255) / 256, 256, 0, stream>>>(W_fc, Wh, count);
    k_fused<<<GRID_FUSED, 256, 0, stream>>>(h, Wh, W_attn, dst, z, a_src, a_dst, count, pos);
    k_scan_block<<<NB_SCAN, 1024, 0, stream>>>(count, rowptr, bsum);
    k_scan_add<<<(N_NODES + 255) / 256, 256, 0, stream>>>(rowptr, bsum);
    k_scatter<<<(N_EDGES + 255) / 256, 256, 0, stream>>>(src, dst, rowptr, pos, csr_src);
    k_aggregate<<<(N_NODES + 3) / 4, 256, 0, stream>>>(rowptr, csr_src, a_src, a_dst, z, out);
}